// Round 1
// baseline (526.280 us; speedup 1.0000x reference)
//
#include <hip/hip_runtime.h>
#include <cstdint>

#define N 8192
#define FIN 256
#define FOUT 128
#define ALPHA 0.2f
#define TJ 256      // j-tile for kernel 2
#define SST 264     // S row stride in u16 (256 + 8 pad -> 2-way LDS conflicts only)

typedef unsigned short u16;
typedef __attribute__((ext_vector_type(8))) short short8;
typedef __attribute__((ext_vector_type(4))) float floatx4;

__device__ __forceinline__ u16 bf16_rne(float f) {
  uint32_t u = __float_as_uint(f);
  u += 0x7fff + ((u >> 16) & 1);
  return (u16)(u >> 16);
}

// Kernel 1: h = x@W in fp32; write hT (bf16, [FOUT][N]); src = h@a1, dst = h@a2.
// Block = 256 threads handles 16 rows. x accessed via wave-uniform (scalar) loads:
// readfirstlane(t>>7) forces SMEM path so the 8-way row reuse costs no VALU/LDS.
__global__ __launch_bounds__(256) void k_proj(const float* __restrict__ x,
                                              const float* __restrict__ W,
                                              const float* __restrict__ a,
                                              u16* __restrict__ hT,
                                              float* __restrict__ srcv,
                                              float* __restrict__ dstv) {
  __shared__ float partS[4][8], partD[4][8];
  const int t = threadIdx.x;
  const int R0 = blockIdx.x * 16;
  const int c = t & 127;                                  // output column
  const int rgu = __builtin_amdgcn_readfirstlane(t >> 7); // row group 0/1 (wave-uniform)
  const float* xrow = x + (size_t)(R0 + rgu * 8) * FIN;

  float acc[8] = {0.f,0.f,0.f,0.f,0.f,0.f,0.f,0.f};
  #pragma unroll 4
  for (int k = 0; k < FIN; ++k) {
    float w = W[k * FOUT + c];   // coalesced, L1/L2-cached across blocks
    #pragma unroll
    for (int i = 0; i < 8; ++i) acc[i] = fmaf(xrow[i * FIN + k], w, acc[i]);
  }

  // hT[c][R0 + rgu*8 .. +8) as one 16B store
  union { u16 u[8]; int4 v; } pk;
  #pragma unroll
  for (int i = 0; i < 8; ++i) pk.u[i] = bf16_rne(acc[i]);
  *(int4*)(hT + (size_t)c * N + R0 + rgu * 8) = pk.v;

  // src/dst: reduce acc[i]*a over the 128 columns (2 waves per row group)
  float a1 = a[c], a2 = a[FOUT + c];
  float s8[8], d8[8];
  #pragma unroll
  for (int i = 0; i < 8; ++i) { s8[i] = acc[i] * a1; d8[i] = acc[i] * a2; }
  #pragma unroll
  for (int off = 32; off > 0; off >>= 1) {
    #pragma unroll
    for (int i = 0; i < 8; ++i) {
      s8[i] += __shfl_down(s8[i], off);
      d8[i] += __shfl_down(d8[i], off);
    }
  }
  const int wv = t >> 6, lane = t & 63;
  if (lane == 0) {
    #pragma unroll
    for (int i = 0; i < 8; ++i) { partS[wv][i] = s8[i]; partD[wv][i] = d8[i]; }
  }
  __syncthreads();
  if (t < 32) {
    int i = t & 7, rg2 = (t >> 3) & 1, which = t >> 4;
    if (which == 0) srcv[R0 + rg2 * 8 + i] = partS[rg2*2][i] + partS[rg2*2+1][i];
    else            dstv[R0 + rg2 * 8 + i] = partD[rg2*2][i] + partD[rg2*2+1][i];
  }
}

// Kernel 2: fused masked-softmax attention. Block = 16 query rows, 256 threads (4 waves).
// Per j-tile (256 cols): p = adj ? exp(leakyrelu(src+dst)) : 0 -> bf16 S tile in LDS,
// row sums l via shuffles, then P@h with mfma_f32_16x16x32_bf16.
// Wave w owns output cols [32w, 32w+32): two 16-col n-tiles.
__global__ __launch_bounds__(256) void k_gat(const int* __restrict__ adj,
                                             const u16* __restrict__ hT,
                                             const float* __restrict__ srcv,
                                             const float* __restrict__ dstv,
                                             float* __restrict__ out) {
  __shared__ u16 S[16 * SST];
  __shared__ float lsh[16];
  const int t = threadIdx.x;
  const int R0 = blockIdx.x * 16;
  const int r  = t >> 4;            // query row 0..15 (p-compute phase)
  const int jl = (t & 15) * 16;     // 16 j's per thread within the tile
  const int lane = t & 63;
  const int wv = t >> 6;
  const int q = lane >> 4, m = lane & 15;   // MFMA lane decomposition
  const int n0 = wv * 32;

  const float srcr = srcv[R0 + r];
  if (t < 16) lsh[t] = 0.0f;
  __syncthreads();

  floatx4 acc0 = {0.f,0.f,0.f,0.f}, acc1 = {0.f,0.f,0.f,0.f};
  const int4*   adjv  = (const int4*)(adj + (size_t)(R0 + r) * N);
  const float4* dstv4 = (const float4*)dstv;
  const u16* hb0 = hT + (size_t)(n0 + m) * N + q * 8;       // B-frag base, n-tile 0
  const u16* hb1 = hb0 + (size_t)16 * N;                    // n-tile 1

  for (int jt = 0; jt < N / TJ; ++jt) {
    const int j0 = jt * TJ;
    union { u16 u[16]; int4 v[2]; } pk;
    float lsum = 0.f;
    #pragma unroll
    for (int g = 0; g < 4; ++g) {
      int4   A = adjv[(j0 + jl) / 4 + g];
      float4 D = dstv4[(j0 + jl) / 4 + g];
      int   ai[4] = {A.x, A.y, A.z, A.w};
      float df[4] = {D.x, D.y, D.z, D.w};
      #pragma unroll
      for (int i = 0; i < 4; ++i) {
        float v = srcr + df[i];
        v = v > 0.f ? v : ALPHA * v;
        float p = ai[i] > 0 ? __expf(v) : 0.f;
        lsum += p;
        pk.u[g * 4 + i] = bf16_rne(p);
      }
    }
    *(int4*)(&S[r * SST + jl])     = pk.v[0];
    *(int4*)(&S[r * SST + jl + 8]) = pk.v[1];
    // reduce lsum over the 16 lanes sharing row r
    lsum += __shfl_xor(lsum, 1);
    lsum += __shfl_xor(lsum, 2);
    lsum += __shfl_xor(lsum, 4);
    lsum += __shfl_xor(lsum, 8);
    if ((t & 15) == 0) lsh[r] += lsum;   // single writer per r
    __syncthreads();

    const u16* hp0 = hb0 + j0;
    const u16* hp1 = hb1 + j0;
    #pragma unroll
    for (int kk = 0; kk < TJ / 32; ++kk) {
      short8 afrag = *(const short8*)(&S[m * SST + kk * 32 + q * 8]);
      short8 b0 = *(const short8*)(hp0 + kk * 32);
      short8 b1 = *(const short8*)(hp1 + kk * 32);
      acc0 = __builtin_amdgcn_mfma_f32_16x16x32_bf16(afrag, b0, acc0, 0, 0, 0);
      acc1 = __builtin_amdgcn_mfma_f32_16x16x32_bf16(afrag, b1, acc1, 0, 0, 0);
    }
    __syncthreads();
  }

  // epilogue: D row = q*4+ri, col = n0 (+16) + m; normalize by l
  #pragma unroll
  for (int ri = 0; ri < 4; ++ri) {
    int row = q * 4 + ri;
    float inv = 1.0f / lsh[row];
    out[(size_t)(R0 + row) * FOUT + n0 + m]      = acc0[ri] * inv;
    out[(size_t)(R0 + row) * FOUT + n0 + 16 + m] = acc1[ri] * inv;
  }
}

extern "C" void kernel_launch(void* const* d_in, const int* in_sizes, int n_in,
                              void* d_out, int out_size, void* d_ws, size_t ws_size,
                              hipStream_t stream) {
  const float* x   = (const float*)d_in[0];
  const int*   adj = (const int*)d_in[1];
  const float* W   = (const float*)d_in[2];
  const float* a   = (const float*)d_in[3];
  float* out = (float*)d_out;

  u16*   hT   = (u16*)d_ws;                                        // 2 MB
  float* srcv = (float*)((char*)d_ws + (size_t)FOUT * N * sizeof(u16));
  float* dstv = srcv + N;

  k_proj<<<N / 16, 256, 0, stream>>>(x, W, a, hT, srcv, dstv);
  k_gat <<<N / 16, 256, 0, stream>>>(adj, hT, srcv, dstv, out);
}

// Round 2
// 450.227 us; speedup vs baseline: 1.1689x; 1.1689x over previous
//
#include <hip/hip_runtime.h>
#include <cstdint>

#define N 8192
#define FIN 256
#define FOUT 128
#define ALPHA 0.2f
#define TJ 256       // j-tile
#define SST 264      // S row stride (u16): 256 + 8 pad
#define KSPLIT 2
#define JPER (N / KSPLIT)   // 4096 j's per block
#define NT (JPER / TJ)      // 16 tiles

typedef unsigned short u16;
typedef __attribute__((ext_vector_type(8))) short short8;
typedef __attribute__((ext_vector_type(4))) float floatx4;

__device__ __forceinline__ u16 bf16_rne(float f) {
  uint32_t u = __float_as_uint(f);
  u += 0x7fff + ((u >> 16) & 1);
  return (u16)(u >> 16);
}

// ---------------------------------------------------------------------------
// Kernel 1: h = x@W (fp32) -> hT bf16 [FOUT][N]; src = h@a1, dst = h@a2.
// 512 blocks x 256 thr, 16 rows/block. x staged in LDS (coalesced float4),
// inner loop reads xs via wave-uniform b128 broadcasts (v1's scalar-load
// chain cost ~29 us; this should be ~8 us).
// ---------------------------------------------------------------------------
__global__ __launch_bounds__(256) void k_proj(const float* __restrict__ x,
                                              const float* __restrict__ W,
                                              const float* __restrict__ a,
                                              u16* __restrict__ hT,
                                              float* __restrict__ srcv,
                                              float* __restrict__ dstv) {
  __shared__ float xs[16 * FIN];                    // 16 KB
  __shared__ float partS[4][8], partD[4][8];
  const int t = threadIdx.x;
  const int R0 = blockIdx.x * 16;

  const float4* xv = (const float4*)(x + (size_t)R0 * FIN);
  float4* xsv = (float4*)xs;
  #pragma unroll
  for (int i = 0; i < 4; ++i) xsv[i * 256 + t] = xv[i * 256 + t];
  __syncthreads();

  const int c = t & 127;            // output column
  const int rg = (t >> 7) * 8;      // row group base (wave-uniform)

  float acc[8] = {0.f,0.f,0.f,0.f,0.f,0.f,0.f,0.f};
  #pragma unroll 2
  for (int k4 = 0; k4 < FIN / 4; ++k4) {
    const float w0 = W[(k4 * 4 + 0) * FOUT + c];
    const float w1 = W[(k4 * 4 + 1) * FOUT + c];
    const float w2 = W[(k4 * 4 + 2) * FOUT + c];
    const float w3 = W[(k4 * 4 + 3) * FOUT + c];
    #pragma unroll
    for (int i = 0; i < 8; ++i) {
      const float4 xq = *(const float4*)&xs[(rg + i) * FIN + k4 * 4];
      acc[i] += xq.x * w0 + xq.y * w1 + xq.z * w2 + xq.w * w3;
    }
  }

  // hT[c][R0+rg .. +8) as one 16B store
  union { u16 u[8]; int4 v; } pk;
  #pragma unroll
  for (int i = 0; i < 8; ++i) pk.u[i] = bf16_rne(acc[i]);
  *(int4*)(hT + (size_t)c * N + R0 + rg) = pk.v;

  // src/dst row reductions (2 waves per row group share via shuffles + LDS)
  const float a1 = a[c], a2 = a[FOUT + c];
  float s8[8], d8[8];
  #pragma unroll
  for (int i = 0; i < 8; ++i) { s8[i] = acc[i] * a1; d8[i] = acc[i] * a2; }
  #pragma unroll
  for (int off = 32; off > 0; off >>= 1) {
    #pragma unroll
    for (int i = 0; i < 8; ++i) {
      s8[i] += __shfl_down(s8[i], off);
      d8[i] += __shfl_down(d8[i], off);
    }
  }
  const int wv = t >> 6, lane = t & 63;
  if (lane == 0) {
    #pragma unroll
    for (int i = 0; i < 8; ++i) { partS[wv][i] = s8[i]; partD[wv][i] = d8[i]; }
  }
  __syncthreads();
  if (t < 32) {
    int i = t & 7, rg2 = (t >> 3) & 1, which = t >> 4;
    if (which == 0) srcv[R0 + rg2 * 8 + i] = partS[rg2*2][i] + partS[rg2*2+1][i];
    else            dstv[R0 + rg2 * 8 + i] = partD[rg2*2][i] + partD[rg2*2+1][i];
  }
}

// ---------------------------------------------------------------------------
// Kernel 2: fused masked softmax-attention partials. 1024 blocks:
// bm = blockIdx&511 -> 16 query rows, ks = blockIdx>>9 -> j in [ks*4096,+4096).
// Pipeline per tile: [b-frags->regs | adj(next)->mask | p-compute -> S[buf]]
// -> ONE barrier -> MFMA. S double-buffered so the second barrier is gone.
// adj carried across iterations as 16-bit mask (1 VGPR) to stay <=~128 VGPRs.
// Stores raw P-partial + l-partial; k_norm combines.
// ---------------------------------------------------------------------------
__global__ __launch_bounds__(256, 4) void k_gat(const int* __restrict__ adj,
                                                const u16* __restrict__ hT,
                                                const float* __restrict__ srcv,
                                                const float* __restrict__ dstv,
                                                float* __restrict__ P,
                                                float* __restrict__ pl) {
  __shared__ u16 S[2][16 * SST];                    // 16.5 KB
  const int t = threadIdx.x;
  const int bm = blockIdx.x & (N / 16 - 1);
  const int ks = blockIdx.x >> 9;
  const int R0 = bm * 16;
  const int J0 = ks * JPER;
  const int r  = t >> 4;              // p-phase query row 0..15
  const int cl = (t & 15) * 4;        // contiguous col base within row-group
  const int lane = t & 63, wv = t >> 6;
  const int q = lane >> 4, m = lane & 15;
  const int n0 = wv * 32;

  const float srcr = srcv[R0 + r];
  const int*   adjrow = adj + (size_t)(R0 + r) * N + J0;
  const float* dstp   = dstv + J0;
  const u16* hb0 = hT + (size_t)(n0 + m) * N + J0 + q * 8;
  const u16* hb1 = hb0 + (size_t)16 * N;

  floatx4 acc0 = {0.f,0.f,0.f,0.f}, acc1 = {0.f,0.f,0.f,0.f};
  float lsum = 0.f;

  // prologue: load tile 0 adj, compress to mask
  uint32_t msk = 0;
  {
    int4 A[4];
    #pragma unroll
    for (int g = 0; g < 4; ++g) A[g] = *(const int4*)(adjrow + cl + g * 64);
    #pragma unroll
    for (int g = 0; g < 4; ++g) {
      int ai[4] = {A[g].x, A[g].y, A[g].z, A[g].w};
      #pragma unroll
      for (int i = 0; i < 4; ++i) msk |= (ai[i] > 0 ? 1u : 0u) << (g * 4 + i);
    }
  }

  for (int jt = 0; jt < NT; ++jt) {
    const int buf = jt & 1;
    const int j0 = jt * TJ;

    // (1) b-frags for THIS tile -> regs (issued early; L2-resident hT)
    short8 bf0[8], bf1[8];
    #pragma unroll
    for (int kk = 0; kk < 8; ++kk) {
      bf0[kk] = *(const short8*)(hb0 + j0 + kk * 32);
      bf1[kk] = *(const short8*)(hb1 + j0 + kk * 32);
    }
    // (2) prefetch NEXT tile's adj (HBM, consumed at end of body)
    const int jn = (jt + 1 < NT) ? jt + 1 : jt;
    int4 An[4];
    #pragma unroll
    for (int g = 0; g < 4; ++g)
      An[g] = *(const int4*)(adjrow + jn * TJ + cl + g * 64);

    // (3) p-compute from carried mask + fresh dst loads -> S[buf]
    u16* Srow = &S[buf][r * SST];
    #pragma unroll
    for (int g = 0; g < 4; ++g) {
      const float4 D = *(const float4*)(dstp + j0 + cl + g * 64);
      float df[4] = {D.x, D.y, D.z, D.w};
      union { u16 u[4]; uint2 v; } pk;
      #pragma unroll
      for (int i = 0; i < 4; ++i) {
        float v = srcr + df[i];
        v = v > 0.f ? v : ALPHA * v;
        float e = __expf(v);
        float p = ((msk >> (g * 4 + i)) & 1u) ? e : 0.f;
        lsum += p;
        pk.u[i] = bf16_rne(p);
      }
      *(uint2*)(Srow + cl + g * 64) = pk.v;
    }

    __syncthreads();   // single barrier per tile (S is double-buffered)

    // (4) MFMA over S[buf] + preloaded b-frags
    const u16* Sm = &S[buf][m * SST];
    #pragma unroll
    for (int kk = 0; kk < 8; ++kk) {
      short8 af = *(const short8*)(Sm + kk * 32 + q * 8);
      acc0 = __builtin_amdgcn_mfma_f32_16x16x32_bf16(af, bf0[kk], acc0, 0, 0, 0);
      acc1 = __builtin_amdgcn_mfma_f32_16x16x32_bf16(af, bf1[kk], acc1, 0, 0, 0);
    }

    // (5) compress prefetched adj -> mask for next iteration
    uint32_t mn = 0;
    #pragma unroll
    for (int g = 0; g < 4; ++g) {
      int ai[4] = {An[g].x, An[g].y, An[g].z, An[g].w};
      #pragma unroll
      for (int i = 0; i < 4; ++i) mn |= (ai[i] > 0 ? 1u : 0u) << (g * 4 + i);
    }
    msk = mn;
  }

  // l-partial: reduce over the 16 threads sharing row r (within one wave)
  lsum += __shfl_xor(lsum, 1);
  lsum += __shfl_xor(lsum, 2);
  lsum += __shfl_xor(lsum, 4);
  lsum += __shfl_xor(lsum, 8);
  if ((t & 15) == 0) pl[(size_t)ks * N + R0 + r] = lsum;

  // raw partial store (C/D layout: row = q*4+ri, col = n0(+16)+m)
  float* Pr = P + ((size_t)ks * N + R0) * FOUT;
  #pragma unroll
  for (int ri = 0; ri < 4; ++ri) {
    const int row = q * 4 + ri;
    Pr[(size_t)row * FOUT + n0 + m]      = acc0[ri];
    Pr[(size_t)row * FOUT + n0 + 16 + m] = acc1[ri];
  }
}

// ---------------------------------------------------------------------------
// Kernel 3: combine k-split partials and normalize. 12.6 MB traffic, ~3 us.
// ---------------------------------------------------------------------------
__global__ __launch_bounds__(256) void k_norm(const float* __restrict__ P,
                                              const float* __restrict__ pl,
                                              float* __restrict__ out) {
  const int idx = blockIdx.x * 256 + threadIdx.x;   // 0 .. N*32-1
  const int rr = idx >> 5;
  const int c4 = (idx & 31) * 4;
  const float inv = 1.0f / (pl[rr] + pl[N + rr]);
  const float4 p0 = *(const float4*)(P + (size_t)rr * FOUT + c4);
  const float4 p1 = *(const float4*)(P + ((size_t)N + rr) * FOUT + c4);
  float4 o;
  o.x = (p0.x + p1.x) * inv;
  o.y = (p0.y + p1.y) * inv;
  o.z = (p0.z + p1.z) * inv;
  o.w = (p0.w + p1.w) * inv;
  *(float4*)(out + (size_t)rr * FOUT + c4) = o;
}

extern "C" void kernel_launch(void* const* d_in, const int* in_sizes, int n_in,
                              void* d_out, int out_size, void* d_ws, size_t ws_size,
                              hipStream_t stream) {
  const float* x   = (const float*)d_in[0];
  const int*   adj = (const int*)d_in[1];
  const float* W   = (const float*)d_in[2];
  const float* a   = (const float*)d_in[3];
  float* out = (float*)d_out;

  char* ws = (char*)d_ws;
  u16*   hT   = (u16*)ws;                 ws += (size_t)FOUT * N * sizeof(u16); // 2 MB
  float* srcv = (float*)ws;               ws += (size_t)N * sizeof(float);
  float* dstv = (float*)ws;               ws += (size_t)N * sizeof(float);
  float* P    = (float*)ws;               ws += (size_t)KSPLIT * N * FOUT * sizeof(float); // 8 MB
  float* pl   = (float*)ws;               ws += (size_t)KSPLIT * N * sizeof(float);

  k_proj<<<N / 16, 256, 0, stream>>>(x, W, a, hT, srcv, dstv);
  k_gat <<<(N / 16) * KSPLIT, 256, 0, stream>>>(adj, hT, srcv, dstv, P, pl);
  k_norm<<<(N * FOUT / 4) / 256, 256, 0, stream>>>(P, pl, out);
}